// Round 10
// baseline (434.876 us; speedup 1.0000x reference)
//
#include <hip/hip_runtime.h>
#include <hip/hip_bf16.h>

#define NTOK 16384
#define CDIM 256
#define INNER 1024
#define WW 128
#define HH 128

typedef unsigned short bf16_t;
typedef __bf16 bf16x8 __attribute__((ext_vector_type(8)));
typedef float f32x4 __attribute__((ext_vector_type(4)));

__device__ __forceinline__ float bf2f(bf16_t u) {
    union { unsigned int i; float f; } x;
    x.i = ((unsigned int)u) << 16;
    return x.f;
}
__device__ __forceinline__ bf16_t f2bf(float f) {
    union { float f; unsigned int i; } x;
    x.f = f;
    unsigned int r = x.i + 0x7FFFu + ((x.i >> 16) & 1u);
    return (bf16_t)(r >> 16);
}
__device__ __forceinline__ ushort2 pk2bf(float a, float b) {
    __hip_bfloat162 h = __float22bfloat162_rn(float2{a, b});
    return *(ushort2*)&h;
}

// two-batch workspace byte offsets (total 218,767,360 B)
static const size_t OFF_XN   = 0;          // bf16 [2][256][16384] -> OUTC after k1
static const size_t OFF_OUTC = 0;
static const size_t OFF_Q    = 16777216;   // bf16 [2][1024][16384] -> VT after k2
static const size_t OFF_VT   = 16777216;
static const size_t OFF_K    = 83886080;   // bf16 [2][1024][16384] -> XO after k2
static const size_t OFF_XO   = 83886080;
static const size_t OFF_V    = 150994944;  // bf16 [2][1024][16384] -> VP/PE2/WBF after kT
static const size_t OFF_VP   = 150994944;
static const size_t OFF_PE2  = 184549376;
static const size_t OFF_WBF  = 201326592;
static const size_t OFF_S    = 218103808;  // f32 [2][16][64][64]; attn bf16 in-place after k3
static const size_t OFF_SSQ  = 218628096;
static const size_t OFF_SSK  = 218636288;
static const size_t OFF_WF   = 218644480;  // f32 [3][1024][10] folded conv+BN

// ---------------- K_PREP: fold BN into conv weights: w' = w*sc, sh ----------------
__global__ __launch_bounds__(256) void k_prep(
    const float* __restrict__ wq, const float* __restrict__ wk, const float* __restrict__ wv,
    const float* __restrict__ qg, const float* __restrict__ qb, const float* __restrict__ qm, const float* __restrict__ qv,
    const float* __restrict__ kg, const float* __restrict__ kb, const float* __restrict__ km, const float* __restrict__ kv_,
    const float* __restrict__ vg, const float* __restrict__ vb, const float* __restrict__ vm, const float* __restrict__ vv,
    float* __restrict__ wf) {
    int id = blockIdx.x * 256 + threadIdx.x;
    if (id >= 3072) return;
    int p = id >> 10, oc = id & 1023;
    const float* w = (p == 0) ? wq : ((p == 1) ? wk : wv);
    const float* g = (p == 0) ? qg : ((p == 1) ? kg : vg);
    const float* be = (p == 0) ? qb : ((p == 1) ? kb : vb);
    const float* m = (p == 0) ? qm : ((p == 1) ? km : vm);
    const float* va = (p == 0) ? qv : ((p == 1) ? kv_ : vv);
    float sc = g[oc] * rsqrtf(va[oc] + 1e-5f);
    float sh = be[oc] - m[oc] * sc;
    float* d = wf + (size_t)id * 10;
#pragma unroll
    for (int t = 0; t < 9; t++) d[t] = w[(size_t)oc * 9 + t] * sc;
    d[9] = sh;
}

// ---------------- K0: x [b][t][256] f32 -> xn [b][c][16384] bf16 ----------------
__global__ __launch_bounds__(256) void k0_transpose(const float* __restrict__ x,
                                                    bf16_t* __restrict__ xn) {
    __shared__ bf16_t tile[32][33];
    int b = blockIdx.z;
    const float* xb = x + (size_t)b * NTOK * CDIM;
    bf16_t* xnb = xn + (size_t)b * CDIM * NTOK;
    int t0 = blockIdx.x * 32;
    int c0 = blockIdx.y * 32;
    int tx = threadIdx.x & 31, ty = threadIdx.x >> 5;
#pragma unroll
    for (int l = 0; l < 4; l++) {
        int t = t0 + ty + l * 8;
        tile[ty + l * 8][tx] = f2bf(xb[(size_t)t * CDIM + c0 + tx]);
    }
    __syncthreads();
#pragma unroll
    for (int l = 0; l < 4; l++) {
        int c = c0 + ty + l * 8;
        xnb[(size_t)c * NTOK + t0 + tx] = tile[tx][ty + l * 8];
    }
}

// ---------------- K1: grouped conv3x3 (BN-folded) -> q,k,v bf16 + sumsq ----------------
// Coalesced uint staging; thread = (row, 4 cols); b128 tap reads; ushort4 stores.
__global__ __launch_bounds__(256) void k1_qkv(
    const bf16_t* __restrict__ xn, const float* __restrict__ wf,
    bf16_t* __restrict__ qo, bf16_t* __restrict__ ko, bf16_t* __restrict__ vo,
    float* __restrict__ ssq, float* __restrict__ ssk) {
    int ychunk = blockIdx.x;   // 0..15
    int cin = blockIdx.y;      // 0..255
    int b = blockIdx.z;
    int y0 = ychunk * 8;
    __shared__ float taps[10][132];
    const bf16_t* plane = xn + ((size_t)(b * CDIM + cin)) * NTOK;
    // interior: 10 rows x 64 uint units (2 tokens each), coalesced
    for (int u = threadIdx.x; u < 640; u += 256) {
        int i = u >> 6, j = u & 63;
        int gy = y0 - 1 + i;
        float v0 = 0.f, v1 = 0.f;
        if (gy >= 0 && gy < HH) {
            unsigned int pr = *(const unsigned int*)&plane[gy * WW + 2 * j];
            v0 = bf2f((bf16_t)(pr & 0xffffu));
            v1 = bf2f((bf16_t)(pr >> 16));
        }
        taps[i][2 * j + 1] = v0;
        taps[i][2 * j + 2] = v1;
    }
    if (threadIdx.x < 20) {  // halo cols gx=-1 (c=0) and gx=128 (c=129) are zero
        int i = threadIdx.x >> 1;
        taps[i][(threadIdx.x & 1) ? 129 : 0] = 0.f;
    }
    __syncthreads();
    int r = threadIdx.x >> 5;          // 0..7 (wave covers 2 rows)
    int c4 = (threadIdx.x & 31) * 4;   // 0..124
    // tap window rows r..r+2, cols c4..c4+5 via aligned float4 reads
    float4 a0 = *(const float4*)&taps[r][c4];
    float4 a1 = *(const float4*)&taps[r][c4 + 4];
    float4 b0 = *(const float4*)&taps[r + 1][c4];
    float4 b1 = *(const float4*)&taps[r + 1][c4 + 4];
    float4 d0 = *(const float4*)&taps[r + 2][c4];
    float4 d1 = *(const float4*)&taps[r + 2][c4 + 4];
    float t0[6] = {a0.x, a0.y, a0.z, a0.w, a1.x, a1.y};
    float t1[6] = {b0.x, b0.y, b0.z, b0.w, b1.x, b1.y};
    float t2[6] = {d0.x, d0.y, d0.z, d0.w, d1.x, d1.y};
    int ocb = cin * 4;
    size_t obase = (size_t)b * 16777216 + (size_t)ocb * NTOK + (size_t)(y0 + r) * WW + c4;
#pragma unroll 1
    for (int p = 0; p < 3; p++) {
        bf16_t* op = (p == 0) ? qo : ((p == 1) ? ko : vo);
        const float* wfp = wf + (size_t)(p * 1024 + ocb) * 10;
        float ssl[4];
#pragma unroll
        for (int s = 0; s < 4; s++) {
            const float* w = wfp + s * 10;
            float w0 = w[0], w1 = w[1], w2 = w[2], w3 = w[3], w4 = w[4],
                  w5 = w[5], w6 = w[6], w7 = w[7], w8 = w[8], sh = w[9];
            float o0 = sh + w0*t0[0] + w1*t0[1] + w2*t0[2]
                          + w3*t1[0] + w4*t1[1] + w5*t1[2]
                          + w6*t2[0] + w7*t2[1] + w8*t2[2];
            float o1 = sh + w0*t0[1] + w1*t0[2] + w2*t0[3]
                          + w3*t1[1] + w4*t1[2] + w5*t1[3]
                          + w6*t2[1] + w7*t2[2] + w8*t2[3];
            float o2 = sh + w0*t0[2] + w1*t0[3] + w2*t0[4]
                          + w3*t1[2] + w4*t1[3] + w5*t1[4]
                          + w6*t2[2] + w7*t2[3] + w8*t2[4];
            float o3 = sh + w0*t0[3] + w1*t0[4] + w2*t0[5]
                          + w3*t1[3] + w4*t1[4] + w5*t1[5]
                          + w6*t2[3] + w7*t2[4] + w8*t2[5];
            ushort2 lo = pk2bf(o0, o1), hi = pk2bf(o2, o3);
            ushort4 st; st.x = lo.x; st.y = lo.y; st.z = hi.x; st.w = hi.y;
            *(ushort4*)&op[obase + (size_t)s * NTOK] = st;
            ssl[s] = o0 * o0 + o1 * o1 + o2 * o2 + o3 * o3;
        }
        if (p < 2) {
            float* ssdst = (p == 0) ? ssq : ssk;
#pragma unroll
            for (int s = 0; s < 4; s++) {
                float v = ssl[s];
#pragma unroll
                for (int o = 32; o > 0; o >>= 1) v += __shfl_down(v, o, 64);
                if ((threadIdx.x & 63) == 0) atomicAdd(&ssdst[b * INNER + ocb + s], v);
            }
        }
    }
}

// ---------------- K2 (MFMA): S[bh][d][e] += sum_t k[d,t]*q[e,t], split-K atomics ----------------
__global__ __launch_bounds__(256) void k2_mfma(const bf16_t* __restrict__ qbuf,
                                               const bf16_t* __restrict__ kbuf,
                                               float* __restrict__ S) {
    int chunk = blockIdx.x;  // 0..15, K=1024 each
    int h = blockIdx.y;      // 0..15
    int b = blockIdx.z;
    __shared__ ushort Ks[64][72];
    __shared__ ushort Qs[64][72];
    const bf16_t* kg = kbuf + (size_t)b * 16777216 + (size_t)(h * 64) * NTOK + (size_t)chunk * 1024;
    const bf16_t* qg = qbuf + (size_t)b * 16777216 + (size_t)(h * 64) * NTOK + (size_t)chunk * 1024;
    int tid = threadIdx.x, lane = tid & 63, wave = tid >> 6;
    int wm = wave & 1, wn = wave >> 1;
    int qd = lane >> 4, l16 = lane & 15;
    int r0 = tid >> 3, c0 = (tid & 7) * 8;
    f32x4 acc[2][2];
#pragma unroll
    for (int i = 0; i < 2; i++)
#pragma unroll
        for (int j = 0; j < 2; j++) acc[i][j] = (f32x4){0.f, 0.f, 0.f, 0.f};
#pragma unroll 1
    for (int kc = 0; kc < 1024; kc += 64) {
#pragma unroll
        for (int l = 0; l < 2; l++) {
            int row = r0 + l * 32;
            *(uint4*)&Ks[row][c0] = *(const uint4*)&kg[(size_t)row * NTOK + kc + c0];
            *(uint4*)&Qs[row][c0] = *(const uint4*)&qg[(size_t)row * NTOK + kc + c0];
        }
        __syncthreads();
#pragma unroll
        for (int kk = 0; kk < 64; kk += 32) {
            bf16x8 af[2], bfr[2];
#pragma unroll
            for (int i = 0; i < 2; i++)
                af[i] = *(const bf16x8*)&Ks[wm * 32 + i * 16 + l16][kk + qd * 8];
#pragma unroll
            for (int j = 0; j < 2; j++)
                bfr[j] = *(const bf16x8*)&Qs[wn * 32 + j * 16 + l16][kk + qd * 8];
#pragma unroll
            for (int i = 0; i < 2; i++)
#pragma unroll
                for (int j = 0; j < 2; j++)
                    acc[i][j] = __builtin_amdgcn_mfma_f32_16x16x32_bf16(af[i], bfr[j], acc[i][j], 0, 0, 0);
        }
        __syncthreads();
    }
    float* Sb = S + (size_t)(b * 16 + h) * 4096;
#pragma unroll
    for (int i = 0; i < 2; i++)
#pragma unroll
        for (int j = 0; j < 2; j++)
#pragma unroll
            for (int r = 0; r < 4; r++) {
                int d = wm * 32 + i * 16 + qd * 4 + r;
                int e = wn * 32 + j * 16 + l16;
                atomicAdd(&Sb[(size_t)d * 64 + e], acc[i][j][r]);
            }
}

// ---------------- K3: fold norms+rescale, softmax, write bf16 attn IN PLACE over S ----------------
__global__ __launch_bounds__(64) void k3_softmax(float* __restrict__ S,
                                                 const float* __restrict__ ssq,
                                                 const float* __restrict__ ssk,
                                                 const float* __restrict__ rescale) {
    int bh = blockIdx.x;  // 0..31
    int b = bh >> 4, h = bh & 15;
    int d = threadIdx.x;
    __shared__ float rq[64];
    int cbase = b * INNER + h * 64;
    rq[d] = 1.0f / fmaxf(sqrtf(ssq[cbase + d]), 1e-12f);
    float rk = 1.0f / fmaxf(sqrtf(ssk[cbase + d]), 1e-12f);
    __syncthreads();
    float rsc = rescale[h];
    const float* row = S + (size_t)bh * 4096 + (size_t)d * 64;
    float sv[64];
    float mx = -3.4e38f;
#pragma unroll
    for (int e = 0; e < 64; e++) {
        sv[e] = row[e] * rk * rq[e] * rsc;
        mx = fmaxf(mx, sv[e]);
    }
    float sum = 0.f;
#pragma unroll
    for (int e = 0; e < 64; e++) {
        sv[e] = expf(sv[e] - mx);
        sum += sv[e];
    }
    float inv = 1.0f / sum;
    __syncthreads();  // all reads of S[bh] complete before bf16 overwrite
    ushort* attn = (ushort*)((char*)S + (size_t)bh * 16384);
#pragma unroll
    for (int e = 0; e < 64; e++) attn[d * 64 + e] = f2bf(sv[e] * inv);
}

// ---------------- KT: v [b][c][t] bf16 -> vt [b][t][c] bf16 ----------------
__global__ __launch_bounds__(256) void kT_vtrans(const bf16_t* __restrict__ v,
                                                 bf16_t* __restrict__ vt) {
    __shared__ bf16_t tile[32][33];
    int b = blockIdx.z;
    const bf16_t* in = v + (size_t)b * 16777216;
    bf16_t* out = vt + (size_t)b * 16777216;
    int t0 = blockIdx.x * 32;
    int c0 = blockIdx.y * 32;
    int tx = threadIdx.x & 31, ty = threadIdx.x >> 5;
#pragma unroll
    for (int l = 0; l < 4; l++) {
        int c = c0 + ty + l * 8;
        tile[ty + l * 8][tx] = in[(size_t)c * NTOK + t0 + tx];
    }
    __syncthreads();
#pragma unroll
    for (int l = 0; l < 4; l++) {
        int t = t0 + ty + l * 8;
        out[(size_t)t * INNER + c0 + tx] = tile[tx][ty + l * 8];
    }
}

// ---------------- CVT: proj_w f32 -> bf16 ----------------
__global__ __launch_bounds__(256) void cvt_w(const float* __restrict__ w,
                                             bf16_t* __restrict__ wbf) {
    int i = (blockIdx.x * 256 + threadIdx.x) * 4;
    float4 f = *(const float4*)&w[i];
    ushort4 r;
    r.x = f2bf(f.x); r.y = f2bf(f.y); r.z = f2bf(f.z); r.w = f2bf(f.w);
    *(ushort4*)&wbf[i] = r;
}

// ---------------- K4 (MFMA): xo[d][t] = sum_e attn[d][e] * vt[t][h*64+e] ----------------
__global__ __launch_bounds__(256) void k4_mfma(const float* __restrict__ Sbase,
                                               const bf16_t* __restrict__ vt,
                                               bf16_t* __restrict__ xo) {
    int tt = blockIdx.x;  // 0..127 (128-token tiles)
    int h = blockIdx.y;   // 0..15
    int b = blockIdx.z;
    int bh = b * 16 + h;
    const ushort* attn = (const ushort*)((const char*)Sbase + (size_t)bh * 16384);
    __shared__ ushort As[64][72];
    __shared__ ushort Bs[128][72];
    int tid = threadIdx.x, lane = tid & 63, wave = tid >> 6;
    int wm = wave & 1, wn = wave >> 1;
    int qd = lane >> 4, l16 = lane & 15;
    int r0 = tid >> 3, c0 = (tid & 7) * 8;
#pragma unroll
    for (int l = 0; l < 2; l++) {
        int row = r0 + l * 32;
        *(uint4*)&As[row][c0] = *(const uint4*)&attn[row * 64 + c0];
    }
    const bf16_t* vtb = vt + (size_t)b * 16777216 + (size_t)(tt * 128) * 1024 + h * 64;
#pragma unroll
    for (int l = 0; l < 4; l++) {
        int row = r0 + l * 32;
        *(uint4*)&Bs[row][c0] = *(const uint4*)&vtb[(size_t)row * 1024 + c0];
    }
    __syncthreads();
    f32x4 acc[2][4];
#pragma unroll
    for (int i = 0; i < 2; i++)
#pragma unroll
        for (int j = 0; j < 4; j++) acc[i][j] = (f32x4){0.f, 0.f, 0.f, 0.f};
#pragma unroll
    for (int kk = 0; kk < 64; kk += 32) {
        bf16x8 af[2], bfr[4];
#pragma unroll
        for (int i = 0; i < 2; i++)
            af[i] = *(const bf16x8*)&As[wm * 32 + i * 16 + l16][kk + qd * 8];
#pragma unroll
        for (int j = 0; j < 4; j++)
            bfr[j] = *(const bf16x8*)&Bs[wn * 64 + j * 16 + l16][kk + qd * 8];
#pragma unroll
        for (int i = 0; i < 2; i++)
#pragma unroll
            for (int j = 0; j < 4; j++)
                acc[i][j] = __builtin_amdgcn_mfma_f32_16x16x32_bf16(af[i], bfr[j], acc[i][j], 0, 0, 0);
    }
    bf16_t* xob = xo + (size_t)b * 16777216 + (size_t)(h * 64) * NTOK + (size_t)tt * 128;
#pragma unroll
    for (int i = 0; i < 2; i++)
#pragma unroll
        for (int j = 0; j < 4; j++)
#pragma unroll
            for (int r = 0; r < 4; r++) {
                int d = wm * 32 + i * 16 + qd * 4 + r;
                int t = wn * 64 + j * 16 + l16;
                xob[(size_t)d * NTOK + t] = f2bf(acc[i][j][r]);
            }
}

// ---------------- GEMM-TN (MFMA): C[m][n] = sum_k A[m][k]*B[n][k] + bias ----------------
__global__ __launch_bounds__(256) void gemm_tn(
    const bf16_t* __restrict__ A, const bf16_t* __restrict__ B,
    const float* __restrict__ pb, bf16_t* __restrict__ C,
    int lda, int ldb, int ldc, int K,
    long strideA, long strideB, long strideC, int bias_on_n) {
    int mb = blockIdx.x, nb = blockIdx.y, b = blockIdx.z;
    A += (size_t)b * strideA;
    B += (size_t)b * strideB;
    C += (size_t)b * strideC;
    __shared__ ushort As[128][72];
    __shared__ ushort Bs[128][72];
    int tid = threadIdx.x;
    int lane = tid & 63, wave = tid >> 6;
    int wm = wave & 1, wn = wave >> 1;
    int q = lane >> 4, l16 = lane & 15;
    f32x4 acc[4][4];
#pragma unroll
    for (int i = 0; i < 4; i++)
#pragma unroll
        for (int j = 0; j < 4; j++) acc[i][j] = (f32x4){0.f, 0.f, 0.f, 0.f};
    const bf16_t* Ab = A + (size_t)mb * 128 * lda;
    const bf16_t* Bb = B + (size_t)nb * 128 * ldb;
    int r0 = tid >> 3;
    int c0 = (tid & 7) * 8;
#pragma unroll 1
    for (int kc = 0; kc < K; kc += 64) {
#pragma unroll
        for (int l = 0; l < 4; l++) {
            int row = l * 32 + r0;
            *(uint4*)&As[row][c0] = *(const uint4*)&Ab[(size_t)row * lda + kc + c0];
            *(uint4*)&Bs[row][c0] = *(const uint4*)&Bb[(size_t)row * ldb + kc + c0];
        }
        __syncthreads();
#pragma unroll
        for (int kk = 0; kk < 64; kk += 32) {
            bf16x8 af[4], bfr[4];
#pragma unroll
            for (int i = 0; i < 4; i++)
                af[i] = *(const bf16x8*)&As[wm * 64 + i * 16 + l16][kk + q * 8];
#pragma unroll
            for (int j = 0; j < 4; j++)
                bfr[j] = *(const bf16x8*)&Bs[wn * 64 + j * 16 + l16][kk + q * 8];
#pragma unroll
            for (int i = 0; i < 4; i++)
#pragma unroll
                for (int j = 0; j < 4; j++)
                    acc[i][j] = __builtin_amdgcn_mfma_f32_16x16x32_bf16(af[i], bfr[j], acc[i][j], 0, 0, 0);
        }
        __syncthreads();
    }
#pragma unroll
    for (int i = 0; i < 4; i++) {
#pragma unroll
        for (int j = 0; j < 4; j++) {
            int n = wn * 64 + j * 16 + l16;
            int gn = nb * 128 + n;
#pragma unroll
            for (int r = 0; r < 4; r++) {
                int m = wm * 64 + i * 16 + q * 4 + r;
                int gm = mb * 128 + m;
                float bias = bias_on_n ? pb[gn] : pb[gm];
                C[(size_t)gm * ldc + gn] = f2bf(acc[i][j][r] + bias);
            }
        }
    }
}

// ---------------- K78: fused depthwise 3x3 (GELU) -> depthwise 3x3, pe1 stays in LDS ----------------
__global__ __launch_bounds__(256) void k_pos_fused(const bf16_t* __restrict__ vp,
                                                   const float* __restrict__ w1t,
                                                   const float* __restrict__ w2t,
                                                   bf16_t* __restrict__ pe2) {
    int ychunk = blockIdx.x;  // 0..15
    int ch = blockIdx.y;      // 0..255
    int b = blockIdx.z;
    int y0 = ychunk * 8;
    __shared__ float t1[12][132];
    __shared__ float t2[10][132];
    const bf16_t* plane = vp + (size_t)b * 4194304 + (size_t)ch * NTOK;
    for (int idx = threadIdx.x; idx < 12 * 132; idx += 256) {
        int i = idx / 132, c = idx % 132;
        int gy = y0 - 2 + i, gx = c - 2;
        float val = 0.f;
        if (gy >= 0 && gy < HH && gx >= 0 && gx < WW) val = bf2f(plane[gy * WW + gx]);
        t1[i][c] = val;
    }
    float wa[9], wb[9];
#pragma unroll
    for (int t = 0; t < 9; t++) {
        wa[t] = w1t[(size_t)ch * 9 + t];
        wb[t] = w2t[(size_t)ch * 9 + t];
    }
    __syncthreads();
    for (int idx = threadIdx.x; idx < 10 * 130; idx += 256) {
        int i = idx / 130, c1 = idx % 130;
        int yy = y0 - 1 + i, xx = c1 - 1;
        float val = 0.f;
        if (yy >= 0 && yy < HH && xx >= 0 && xx < WW) {
            float a = wa[0] * t1[i][c1]     + wa[1] * t1[i][c1 + 1]     + wa[2] * t1[i][c1 + 2]
                    + wa[3] * t1[i + 1][c1] + wa[4] * t1[i + 1][c1 + 1] + wa[5] * t1[i + 1][c1 + 2]
                    + wa[6] * t1[i + 2][c1] + wa[7] * t1[i + 2][c1 + 1] + wa[8] * t1[i + 2][c1 + 2];
            val = 0.5f * a * (1.0f + erff(a * 0.70710678118654752f));
        }
        t2[i][c1] = val;
    }
    __syncthreads();
    int x = threadIdx.x & 127;
    int half = threadIdx.x >> 7;
    bf16_t* oplane = pe2 + (size_t)b * 4194304 + (size_t)ch * NTOK;
#pragma unroll
    for (int rp = 0; rp < 4; rp++) {
        int r = rp * 2 + half;
        float acc = wb[0] * t2[r][x]     + wb[1] * t2[r][x + 1]     + wb[2] * t2[r][x + 2]
                  + wb[3] * t2[r + 1][x] + wb[4] * t2[r + 1][x + 1] + wb[5] * t2[r + 1][x + 2]
                  + wb[6] * t2[r + 2][x] + wb[7] * t2[r + 2][x + 1] + wb[8] * t2[r + 2][x + 2];
        oplane[(size_t)(y0 + r) * WW + x] = f2bf(acc);
    }
}

// ---------------- K9: out[t][c] = outc[t][c] + pe2[c][t]  -> f32 output ----------------
__global__ __launch_bounds__(256) void k9_final(const bf16_t* __restrict__ outc,
                                                const bf16_t* __restrict__ pe2,
                                                float* __restrict__ out) {
    __shared__ float tile[32][33];
    int t0 = blockIdx.x * 32;
    int c0 = blockIdx.y * 32;
    int b = blockIdx.z;
    int tx = threadIdx.x & 31, ty = threadIdx.x >> 5;
    const bf16_t* peb = pe2 + (size_t)b * 4194304;
    const bf16_t* ob = outc + (size_t)b * 4194304;
    float* o = out + (size_t)b * 4194304;
#pragma unroll
    for (int l = 0; l < 4; l++) {
        int c = c0 + ty + l * 8;
        tile[ty + l * 8][tx] = bf2f(peb[(size_t)c * NTOK + t0 + tx]);
    }
    __syncthreads();
#pragma unroll
    for (int l = 0; l < 4; l++) {
        int t = t0 + ty + l * 8;
        size_t idx = (size_t)t * CDIM + c0 + tx;
        o[idx] = bf2f(ob[idx]) + tile[tx][ty + l * 8];
    }
}

extern "C" void kernel_launch(void* const* d_in, const int* in_sizes, int n_in,
                              void* d_out, int out_size, void* d_ws, size_t ws_size,
                              hipStream_t stream) {
    const float* x_in    = (const float*)d_in[0];
    const float* wq      = (const float*)d_in[1];
    const float* wk      = (const float*)d_in[2];
    const float* wv      = (const float*)d_in[3];
    const float* qg      = (const float*)d_in[4];
    const float* qb      = (const float*)d_in[5];
    const float* qm      = (const float*)d_in[6];
    const float* qv      = (const float*)d_in[7];
    const float* kg      = (const float*)d_in[8];
    const float* kb      = (const float*)d_in[9];
    const float* km      = (const float*)d_in[10];
    const float* kv_     = (const float*)d_in[11];
    const float* vg      = (const float*)d_in[12];
    const float* vb      = (const float*)d_in[13];
    const float* vm      = (const float*)d_in[14];
    const float* vv      = (const float*)d_in[15];
    const float* rescale = (const float*)d_in[16];
    const float* proj_w  = (const float*)d_in[17];
    const float* proj_b  = (const float*)d_in[18];
    const float* pos_w1  = (const float*)d_in[19];
    const float* pos_w2  = (const float*)d_in[20];

    char* ws = (char*)d_ws;
    bf16_t* xn   = (bf16_t*)(ws + OFF_XN);
    bf16_t* q    = (bf16_t*)(ws + OFF_Q);
    bf16_t* k    = (bf16_t*)(ws + OFF_K);
    bf16_t* v    = (bf16_t*)(ws + OFF_V);
    bf16_t* vt   = (bf16_t*)(ws + OFF_VT);
    bf16_t* xo   = (bf16_t*)(ws + OFF_XO);
    bf16_t* outc = (bf16_t*)(ws + OFF_OUTC);
    bf16_t* vp   = (bf16_t*)(ws + OFF_VP);
    bf16_t* pe2  = (bf16_t*)(ws + OFF_PE2);
    bf16_t* wbf  = (bf16_t*)(ws + OFF_WBF);
    float* S     = (float*)(ws + OFF_S);
    float* ssq   = (float*)(ws + OFF_SSQ);
    float* ssk   = (float*)(ws + OFF_SSK);
    float* wf    = (float*)(ws + OFF_WF);

    hipMemsetAsync(ws + OFF_S, 0, (size_t)540672, stream);

    k_prep<<<dim3(12), 256, 0, stream>>>(wq, wk, wv, qg, qb, qm, qv,
                                         kg, kb, km, kv_, vg, vb, vm, vv, wf);
    k0_transpose<<<dim3(512, 8, 2), 256, 0, stream>>>(x_in, xn);
    k1_qkv<<<dim3(16, 256, 2), 256, 0, stream>>>(xn, wf, q, k, v, ssq, ssk);
    k2_mfma<<<dim3(16, 16, 2), 256, 0, stream>>>(q, k, S);
    k3_softmax<<<dim3(32), 64, 0, stream>>>(S, ssq, ssk, rescale);
    kT_vtrans<<<dim3(512, 32, 2), 256, 0, stream>>>(v, vt);   // q dead -> vt in B
    cvt_w<<<dim3(256), 256, 0, stream>>>(proj_w, wbf);        // v dead -> wbf in D tail
    k4_mfma<<<dim3(128, 16, 2), 256, 0, stream>>>(S, vt, xo); // k dead -> xo in C
    // k5: outc[t][co] = xo_flat[t][:] . W[co][:]   (M=16384,N=256,K=1024)
    gemm_tn<<<dim3(128, 2, 2), 256, 0, stream>>>(xo, wbf, proj_b, outc,
                                                 1024, 1024, 256, 1024,
                                                 16777216L, 0L, 4194304L, 1);
    // k6: vp[co][t] = W[co][:] . vt[t][:]          (M=256,N=16384,K=1024)
    gemm_tn<<<dim3(2, 128, 2), 256, 0, stream>>>(wbf, vt, proj_b, vp,
                                                 1024, 1024, 16384, 1024,
                                                 0L, 16777216L, 4194304L, 0);
    k_pos_fused<<<dim3(16, 256, 2), 256, 0, stream>>>(vp, pos_w1, pos_w2, pe2);
    k9_final<<<dim3(512, 8, 2), 256, 0, stream>>>(outc, pe2, (float*)d_out);
}